// Round 5
// baseline (736.217 us; speedup 1.0000x reference)
//
#include <hip/hip_runtime.h>
#include <cstdint>
#include <cstddef>

#define NLAYERS 24
#define BATCH   4096
#define FEAT    1024

typedef _Float16 half_t;
typedef half_t half8 __attribute__((ext_vector_type(8)));
typedef float  f32x4 __attribute__((ext_vector_type(4)));

// ---------------------------------------------------------------------------
// async global -> LDS, 16B per lane. LDS dest is wave-uniform base + lane*16.
// ---------------------------------------------------------------------------
__device__ __forceinline__ void gload_lds16(const void* g, void* l) {
    __builtin_amdgcn_global_load_lds(
        (__attribute__((address_space(1))) void*)(void*)g,
        (__attribute__((address_space(3))) void*)l,
        16, 0, 0);
}

// ---------------------------------------------------------------------------
// prep_weights: WmT[l][n][k] = (half)(W[l][k][n] * M[l][k][n]),  k,n in [0,1024)
// 64x64 tiles through LDS. Grid = NLAYERS * 16 * 16 blocks of 256 threads.
// ---------------------------------------------------------------------------
__global__ __launch_bounds__(256) void prep_weights(
    const float* __restrict__ W, const float* __restrict__ M,
    half_t* __restrict__ WmT)
{
    __shared__ float tile[64][65];   // +1 pad: 2-way-max bank aliasing (free)

    const int bid = blockIdx.x;
    const int l   = bid >> 8;        // layer
    const int t   = bid & 255;
    const int k0  = (t >> 4) * 64;
    const int n0  = (t & 15) * 64;
    const size_t lbase = (size_t)l * 1025 * 1024;

    const int tid = threadIdx.x;
    const int rr  = tid >> 4;        // 0..15
    const int c4  = (tid & 15) * 4;

#pragma unroll
    for (int i = 0; i < 4; ++i) {
        const int row = rr + i * 16;
        const size_t g = lbase + (size_t)(k0 + row) * 1024 + (n0 + c4);
        const float4 w4 = *(const float4*)(W + g);
        const float4 m4 = *(const float4*)(M + g);
        tile[row][c4 + 0] = w4.x * m4.x;
        tile[row][c4 + 1] = w4.y * m4.y;
        tile[row][c4 + 2] = w4.z * m4.z;
        tile[row][c4 + 3] = w4.w * m4.w;
    }
    __syncthreads();

    // write transposed: 64 n-rows x 64 k-cols, each thread 16 contiguous k (32B)
    const int n   = tid >> 2;        // 0..63
    const int k16 = (tid & 3) * 16;
    half8 lo, hi;
#pragma unroll
    for (int j = 0; j < 8; ++j) {
        lo[j] = (half_t)tile[k16 + j][n];
        hi[j] = (half_t)tile[k16 + 8 + j][n];
    }
    const size_t o = (size_t)l * 1024 * 1024 + (size_t)(n0 + n) * 1024 + (k0 + k16);
    *(half8*)(WmT + o)     = lo;
    *(half8*)(WmT + o + 8) = hi;
}

// ---------------------------------------------------------------------------
// prep_bias: bias[l][n] = W[l][1024][n]  (mask row is forced to 1)
// Grid = 24*1024/256 = 96 blocks.
// ---------------------------------------------------------------------------
__global__ __launch_bounds__(256) void prep_bias(
    const float* __restrict__ W, float* __restrict__ bias)
{
    const int i = blockIdx.x * 256 + threadIdx.x;
    const int l = i >> 10;
    const int n = i & 1023;
    bias[i] = W[(size_t)l * 1025 * 1024 + (size_t)1024 * 1024 + n];
}

// ---------------------------------------------------------------------------
// prep_xcast: act0 = (half)x, 8 elems/thread. Grid = 4096*1024/8/256 = 2048.
// ---------------------------------------------------------------------------
__global__ __launch_bounds__(256) void prep_xcast(
    const float* __restrict__ x, half_t* __restrict__ a0)
{
    const size_t i = ((size_t)blockIdx.x * 256 + threadIdx.x) * 8;
    const float4 u = *(const float4*)(x + i);
    const float4 v = *(const float4*)(x + i + 4);
    half8 h;
    h[0] = (half_t)u.x; h[1] = (half_t)u.y; h[2] = (half_t)u.z; h[3] = (half_t)u.w;
    h[4] = (half_t)v.x; h[5] = (half_t)v.y; h[6] = (half_t)v.z; h[7] = (half_t)v.w;
    *(half8*)(a0 + i) = h;
}

// ---------------------------------------------------------------------------
// gemm_layer: C[4096][1024] = relu(A[4096][1024] @ Wm^T + bias)
//   A  : fp16 row-major [B][K]           (K-contiguous)
//   Bt : fp16 n-major  [N][K]            (K-contiguous -> same frag path as A)
// BM=128 BN=64 BK=32, 256 threads (4 waves, 2x2 of 64x32), 512 blocks (2/CU).
// mfma_f32_16x16x32_f16; C/D layout: col = lane&15, row = (lane>>4)*4 + reg.
// ---------------------------------------------------------------------------
template <int LAST>
__global__ __launch_bounds__(256, 2) void gemm_layer(
    const half_t* __restrict__ A,
    const half_t* __restrict__ Bt,
    const float*  __restrict__ bias,
    half_t* __restrict__ Ch,
    float*  __restrict__ Cf)
{
    __shared__ half_t As[128 * 32];   // 8 KB, linear [128][32]
    __shared__ half_t Bs[64 * 32];    // 4 KB, linear [64][32]

    const int tid  = threadIdx.x;
    const int bid  = blockIdx.x;
    const int bm   = bid >> 4;        // 0..31 (M tiles)
    const int bn   = bid & 15;        // 0..15 (N tiles)
    const int lane = tid & 63;
    const int q    = lane >> 4;       // 0..3
    const int r    = lane & 15;       // 0..15
    const int w    = tid >> 6;        // wave 0..3
    const int wr   = w >> 1;          // wave row 0..1 (64 rows each)
    const int wc   = w & 1;           // wave col 0..1 (32 cols each)

    const half_t* Ab = A  + (size_t)bm * 128 * 1024;
    const half_t* Bb = Bt + (size_t)bn * 64 * 1024;

    // staging: element-chunk e (8 halfs = 16B); e = iter*256 + tid
    const int srow = tid >> 2;            // 0..63
    const int scol = (tid & 3) * 8;       // 0,8,16,24
    const int wbase = (tid & 192) * 8;    // wave-uniform LDS elem base (lane*8 added by HW)

    // fragment LDS element offsets
    const int aoff = (wr * 64 + r) * 32 + q * 8;   // + m*512
    const int boff = (wc * 32 + r) * 32 + q * 8;   // + n*512

    f32x4 acc[4][2];
#pragma unroll
    for (int m = 0; m < 4; ++m)
#pragma unroll
        for (int n = 0; n < 2; ++n)
            acc[m][n] = (f32x4){0.f, 0.f, 0.f, 0.f};

    for (int kt = 0; kt < 32; ++kt) {
        const int k0 = kt * 32;
        __syncthreads();   // previous compute done reading LDS
        gload_lds16(Ab + (size_t)srow * 1024 + k0 + scol,        As + wbase);
        gload_lds16(Ab + (size_t)(64 + srow) * 1024 + k0 + scol, As + 2048 + wbase);
        gload_lds16(Bb + (size_t)srow * 1024 + k0 + scol,        Bs + wbase);
        __syncthreads();   // staging visible (compiler drains vmcnt before barrier)

        half8 a[4], b[2];
#pragma unroll
        for (int m = 0; m < 4; ++m) a[m] = *(const half8*)(As + aoff + m * 512);
#pragma unroll
        for (int n = 0; n < 2; ++n) b[n] = *(const half8*)(Bs + boff + n * 512);
#pragma unroll
        for (int m = 0; m < 4; ++m)
#pragma unroll
            for (int n = 0; n < 2; ++n)
                acc[m][n] = __builtin_amdgcn_mfma_f32_16x16x32_f16(a[m], b[n], acc[m][n], 0, 0, 0);
    }

    // epilogue: bias + relu, store
    const int colb = bn * 64 + wc * 32 + r;
    const int rowb = bm * 128 + wr * 64 + q * 4;
#pragma unroll
    for (int n = 0; n < 2; ++n) {
        const int col = colb + n * 16;
        const float bv = bias[col];
#pragma unroll
        for (int m = 0; m < 4; ++m) {
            const int row = rowb + m * 16;
#pragma unroll
            for (int t = 0; t < 4; ++t) {
                float v = acc[m][n][t] + bv;
                v = v > 0.f ? v : 0.f;
                if (LAST) Cf[(size_t)(row + t) * 1024 + col] = v;
                else      Ch[(size_t)(row + t) * 1024 + col] = (half_t)v;
            }
        }
    }
}

// ---------------------------------------------------------------------------
extern "C" void kernel_launch(void* const* d_in, const int* in_sizes, int n_in,
                              void* d_out, int out_size, void* d_ws, size_t ws_size,
                              hipStream_t stream)
{
    const float* x = (const float*)d_in[0];
    const float* W = (const float*)d_in[1];
    const float* M = (const float*)d_in[2];
    float* out = (float*)d_out;

    // workspace layout (~64.1 MB total)
    half_t* WmT  = (half_t*)d_ws;                                  // 24*1024*1024 fp16
    float*  bias = (float*)(WmT + (size_t)NLAYERS * 1024 * 1024);  // 24*1024 fp32
    half_t* act0 = (half_t*)(bias + NLAYERS * 1024);               // 4096*1024 fp16
    half_t* act1 = act0 + (size_t)BATCH * FEAT;                    // 4096*1024 fp16

    prep_weights<<<dim3(NLAYERS * 256), dim3(256), 0, stream>>>(W, M, WmT);
    prep_bias   <<<dim3(96),            dim3(256), 0, stream>>>(W, bias);
    prep_xcast  <<<dim3(2048),          dim3(256), 0, stream>>>(x, act0);

    half_t* cur = act0;
    half_t* nxt = act1;
    for (int l = 0; l < NLAYERS; ++l) {
        const half_t* Wl = WmT + (size_t)l * 1024 * 1024;
        const float*  bl = bias + l * 1024;
        if (l == NLAYERS - 1) {
            gemm_layer<1><<<dim3(512), dim3(256), 0, stream>>>(cur, Wl, bl, (half_t*)nullptr, out);
        } else {
            gemm_layer<0><<<dim3(512), dim3(256), 0, stream>>>(cur, Wl, bl, nxt, (float*)nullptr);
        }
        half_t* tmp = cur; cur = nxt; nxt = tmp;
    }
}